// Round 9
// baseline (257.051 us; speedup 1.0000x reference)
//
#include <hip/hip_runtime.h>
#include <hip/hip_bf16.h>

#define M_PTS 100000
#define KN 27
#define CS 96
#define NC 13
#define NTILES 1563

// flat output offsets (f32 elements), return order:
// logits[M,13], bdy[M,1], affinity[M,1,27], refined[M,64], neighbor[M,27], mask[M,27]
#define OFF_LOGITS 0ull
#define OFF_BDY    1300000ull
#define OFF_AFF    1400000ull
#define OFF_RF     4100000ull
#define OFF_NBR    10500000ull
#define OFF_MASK   13200000ull

// ws layout (units = shorts/bf16)
#define WS_QG   0ull                    // [M][64] bf16 (all rows)
#define WS_U    6400000ull              // [M][64] bf16 (complex rows only)
#define WS_P    12800000ull             // [M][27] bf16 (complex rows only)
#define WS_WGEO 15500000ull             // [64][72]  WgeoB[d][c] = Wgeo[c][d]
#define WS_WQK  (WS_WGEO + 4608ull)     // [64][72]  WqkB[d][c]  = sum_t Wq[c][t]Wk[d][t]
#define WS_WPOS (WS_WQK + 4608ull)      // [32][72]  rows 0-26: Wq@pos^T; row 27: Wbdy
#define WS_W1   (WS_WPOS + 2304ull)     // [64][104] W1B[d][s] = sum_t Wv[s][t]Wout[t][d]
#define WS_W2   (WS_W1 + 6656ull)       // [16][104] W2B[j][s] = sum_t Wv[s][t]V[t][j]
#define WS_B2   (WS_W2 + 1664ull)       // f32[16]: b2[j] = bout@Wcls[:,j] + bcls[j]
#define WS_VM   (WS_B2 + 32ull)         // u32[M]: per-point valid-lane bitmask

typedef float f4 __attribute__((ext_vector_type(4)));
typedef float f32x4 __attribute__((ext_vector_type(4)));
typedef short bf16x8 __attribute__((ext_vector_type(8)));
typedef short s16x4 __attribute__((ext_vector_type(4)));

__device__ __forceinline__ short f2bf(float f) {
  union { float f; unsigned int u; } x; x.f = f;
  unsigned int r = x.u + 0x7fffu + ((x.u >> 16) & 1u);
  return (short)(r >> 16);
}
__device__ __forceinline__ float bf2f(unsigned short u) {
  union { unsigned int i; float f; } x; x.i = ((unsigned int)u) << 16;
  return x.f;
}
__device__ __forceinline__ bool nbr_is64(const void* nbrv) {
  const int* w = (const int*)nbrv;
  bool is64 = true;
#pragma unroll
  for (int j = 1; j < 64; j += 2) is64 = is64 && (w[j] == 0);
  return is64;
}
__device__ __forceinline__ long long nbr_at(const void* nbrv, bool is64, size_t i) {
  return is64 ? ((const long long*)nbrv)[i] : (long long)((const int*)nbrv)[i];
}

// ---------------- k0: all fused weights, 38 blocks (0-31: main; 32-37: W2/b2) ----------------
__global__ __launch_bounds__(256) void k0(const float* __restrict__ Wgeo,
                                          const float* __restrict__ Wbdy,
                                          const float* __restrict__ Wq,
                                          const float* __restrict__ Wk,
                                          const float* __restrict__ Wv,
                                          const float* __restrict__ pos,
                                          const float* __restrict__ Wout,
                                          const float* __restrict__ bout,
                                          const float* __restrict__ Wcls,
                                          const float* __restrict__ bcls,
                                          short* __restrict__ ws) {
  __shared__ float V[64 * NC];
  const int tid = threadIdx.x, blk = blockIdx.x;
  if (blk < 32) {
    for (int i = blk * 256 + tid; i < 16384; i += 8192) {
      if (i < 4096) {
        const int d = i >> 6, c = i & 63;
        ws[WS_WGEO + d * 72 + c] = f2bf(Wgeo[c * 64 + d]);
      } else if (i < 8192) {
        const int t = i - 4096, d = t >> 6, c = t & 63;
        float s = 0.f;
#pragma unroll 8
        for (int q = 0; q < 64; ++q) s = fmaf(Wq[c * 64 + q], Wk[d * 64 + q], s);
        ws[WS_WQK + d * 72 + c] = f2bf(s);
      } else if (i < 10240) {
        const int t = i - 8192, j = t >> 6, c = t & 63;
        float s = 0.f;
        if (j < 27) {
#pragma unroll 8
          for (int q = 0; q < 64; ++q) s = fmaf(Wq[c * 64 + q], pos[j * 64 + q], s);
        } else if (j == 27) {
          s = Wbdy[c];
        }
        ws[WS_WPOS + j * 72 + c] = f2bf(s);
      } else {
        const int t = i - 10240, d = t / 96, sc = t % 96;
        float a = 0.f;
#pragma unroll 8
        for (int q = 0; q < 64; ++q) a = fmaf(Wv[sc * 64 + q], Wout[q * 64 + d], a);
        ws[WS_W1 + d * 104 + sc] = f2bf(a);
      }
    }
  } else {
    for (int i = tid; i < 64 * NC; i += 256) {
      const int t = i / NC, j = i % NC;
      float a = 0.f;
#pragma unroll 8
      for (int d = 0; d < 64; ++d) a = fmaf(Wout[t * 64 + d], Wcls[d * NC + j], a);
      V[i] = a;
    }
    __syncthreads();
    const int g = (blk - 32) * 256 + tid;
    if (g < 16 * 96) {
      const int j = g / 96, s = g % 96;
      float a = 0.f;
      if (j < NC) {
#pragma unroll 8
        for (int t = 0; t < 64; ++t) a = fmaf(Wv[s * 64 + t], V[t * NC + j], a);
      }
      ws[WS_W2 + j * 104 + s] = f2bf(a);
    }
    if (blk == 32 && tid < 16) {
      float a = 0.f;
      if (tid < NC) {
        for (int d = 0; d < 64; ++d) a = fmaf(bout[d], Wcls[d * NC + tid], a);
        a += bcls[tid];
      }
      ((float*)(ws + WS_B2))[tid] = a;
    }
  }
}

// ---------------- k1: fused main kernel (simple path complete; complex deferred) ----------------
__global__ __launch_bounds__(256) void k1(const float* __restrict__ geo,
                                          const float* __restrict__ sem,
                                          const int* __restrict__ coords,
                                          const void* __restrict__ nbrv,
                                          const float* __restrict__ gamma,
                                          const float* __restrict__ beta,
                                          const float* __restrict__ bbdy,
                                          const float* __restrict__ bout,
                                          const short* __restrict__ ws,
                                          short* __restrict__ Qg,
                                          short* __restrict__ U,
                                          short* __restrict__ P,
                                          unsigned int* __restrict__ vmask,
                                          float* __restrict__ out) {
  __shared__ __align__(16) char sMem[41472];
  __shared__ unsigned sVm[64];
  short* sX   = (short*)sMem;               // [64][72] (phase 1)
  short* sQ   = (short*)(sMem + 9216);      // [64][72] (phase 1)
  short* sWg  = (short*)(sMem + 18432);     // [64][72] (phase 1)
  short* sWqk = (short*)(sMem + 27648);     // [64][72] (phase 1)
  short* sWp  = (short*)(sMem + 36864);     // [32][72] (phase 1)
  short* sS   = (short*)sMem;               // [64][104] (phase 2 overlay)
  short* sW1  = (short*)(sMem + 18432);     // [64][104] (phase 2 overlay)
  short* sW2  = (short*)(sMem + 31744);     // [16][104] (phase 2 overlay)
  float* sB2  = (float*)(sMem + 35072);     // f32[16]  (phase 2 overlay)
  const int tid = threadIdx.x;
  if (tid < 64) sVm[tid] = 0;
  {
    const bf16x8* a = (const bf16x8*)(ws + WS_WGEO);
    const bf16x8* b = (const bf16x8*)(ws + WS_WQK);
    const bf16x8* c = (const bf16x8*)(ws + WS_WPOS);
    for (int i = tid; i < 576; i += 256) ((bf16x8*)sWg)[i] = a[i];
    for (int i = tid; i < 576; i += 256) ((bf16x8*)sWqk)[i] = b[i];
    for (int i = tid; i < 288; i += 256) ((bf16x8*)sWp)[i] = c[i];
  }
  const int m0 = blockIdx.x * 64;
  {
    const int r = tid >> 2, qq = tid & 3;
    const int m = min(m0 + r, M_PTS - 1);
    const f4* g = (const f4*)(geo + (size_t)m * 64 + qq * 16);
    const f4 a = g[0], b = g[1], c = g[2], d = g[3];
    bf16x8 lo, hi;
    lo[0]=f2bf(a.x); lo[1]=f2bf(a.y); lo[2]=f2bf(a.z); lo[3]=f2bf(a.w);
    lo[4]=f2bf(b.x); lo[5]=f2bf(b.y); lo[6]=f2bf(b.z); lo[7]=f2bf(b.w);
    hi[0]=f2bf(c.x); hi[1]=f2bf(c.y); hi[2]=f2bf(c.z); hi[3]=f2bf(c.w);
    hi[4]=f2bf(d.x); hi[5]=f2bf(d.y); hi[6]=f2bf(d.z); hi[7]=f2bf(d.w);
    *(bf16x8*)&sX[r * 72 + qq * 16] = lo;
    *(bf16x8*)&sX[r * 72 + qq * 16 + 8] = hi;
  }
  __syncthreads();

  const int lane = tid & 63, w = tid >> 6;
  const int hi4 = lane >> 4, lo16 = lane & 15;
  const int R = w * 16;

  // GEMM1: g = X @ Wgeo
  f32x4 acc[4] = {};
#pragma unroll
  for (int kk = 0; kk < 2; ++kk) {
    const bf16x8 a = *(const bf16x8*)&sX[(R + lo16) * 72 + kk * 32 + hi4 * 8];
#pragma unroll
    for (int n = 0; n < 4; ++n) {
      const bf16x8 b = *(const bf16x8*)&sWg[(n * 16 + lo16) * 72 + kk * 32 + hi4 * 8];
      acc[n] = __builtin_amdgcn_mfma_f32_16x16x32_bf16(a, b, acc[n], 0, 0, 0);
    }
  }
  // LN + ReLU -> sQ
  float gam4[4], bet4[4];
#pragma unroll
  for (int n = 0; n < 4; ++n) { gam4[n] = gamma[n * 16 + lo16]; bet4[n] = beta[n * 16 + lo16]; }
#pragma unroll
  for (int j = 0; j < 4; ++j) {
    float s = acc[0][j] + acc[1][j] + acc[2][j] + acc[3][j];
#pragma unroll
    for (int o = 1; o <= 8; o <<= 1) s += __shfl_xor(s, o, 64);
    const float mu = s * (1.f / 64.f);
    float vs = 0.f;
#pragma unroll
    for (int n = 0; n < 4; ++n) { const float d = acc[n][j] - mu; vs = fmaf(d, d, vs); }
#pragma unroll
    for (int o = 1; o <= 8; o <<= 1) vs += __shfl_xor(vs, o, 64);
    const float inv = rsqrtf(vs * (1.f / 64.f) + 1e-5f);
#pragma unroll
    for (int n = 0; n < 4; ++n) {
      const float q = fmaxf(fmaf((acc[n][j] - mu) * inv, gam4[n], bet4[n]), 0.f);
      sQ[(R + hi4 * 4 + j) * 72 + n * 16 + lo16] = f2bf(q);
    }
  }
  __syncthreads();
  // GEMM-U, GEMM-P (results stay in regs)
  f32x4 au[4] = {};
  f32x4 ap[2] = {};
#pragma unroll
  for (int kk = 0; kk < 2; ++kk) {
    const bf16x8 a = *(const bf16x8*)&sQ[(R + lo16) * 72 + kk * 32 + hi4 * 8];
#pragma unroll
    for (int n = 0; n < 4; ++n) {
      const bf16x8 b = *(const bf16x8*)&sWqk[(n * 16 + lo16) * 72 + kk * 32 + hi4 * 8];
      au[n] = __builtin_amdgcn_mfma_f32_16x16x32_bf16(a, b, au[n], 0, 0, 0);
    }
#pragma unroll
    for (int n = 0; n < 2; ++n) {
      const bf16x8 b = *(const bf16x8*)&sWp[(n * 16 + lo16) * 72 + kk * 32 + hi4 * 8];
      ap[n] = __builtin_amdgcn_mfma_f32_16x16x32_bf16(a, b, ap[n], 0, 0, 0);
    }
  }
  // neighbor/mask outputs (fully coalesced) + vmask bits via LDS atomics
  const bool is64 = nbr_is64(nbrv);
  for (int idx = tid; idx < 64 * KN; idx += 256) {
    const int p = idx / KN, kq = idx - p * KN;
    const int m = m0 + p;
    if (m < M_PTS) {
      const long long nk = nbr_at(nbrv, is64, (size_t)m * KN + kq);
      const int dx = coords[nk * 3 + 0] - coords[m * 3 + 0];
      const int dy = coords[nk * 3 + 1] - coords[m * 3 + 1];
      const int dz = coords[nk * 3 + 2] - coords[m * 3 + 2];
      const int valid = (max(max(abs(dx), abs(dy)), abs(dz)) <= 1) ? 1 : 0;
      out[OFF_NBR + (size_t)m0 * KN + idx] = (float)nk;
      out[OFF_MASK + (size_t)m0 * KN + idx] = (float)valid;
      if (valid) atomicOr(&sVm[p], 1u << kq);
    }
  }
  __syncthreads();   // sVm complete; sQ stable
  // Qg store (all rows, coalesced)
  for (int i = tid; i < 512; i += 256) {
    const int r = i >> 3, u = i & 7;
    const int m = m0 + r;
    if (m < M_PTS)
      *(bf16x8*)&Qg[(size_t)m * 64 + u * 8] = *(const bf16x8*)&sQ[r * 72 + u * 8];
  }
  // vmask store
  if (tid < 64 && m0 + tid < M_PTS) vmask[m0 + tid] = sVm[tid];
  // bdy (always) + U/P (complex rows only)
  const float bb = bbdy[0];
#pragma unroll
  for (int j = 0; j < 4; ++j) {
    const int row = R + hi4 * 4 + j;
    const int m = m0 + row;
    if (m < M_PTS) {
      const bool cx = __popc(sVm[row]) > 1;
#pragma unroll
      for (int n = 0; n < 4; ++n)
        if (cx) U[(size_t)m * 64 + n * 16 + lo16] = f2bf(au[n][j]);
#pragma unroll
      for (int n = 0; n < 2; ++n) {
        const int col = n * 16 + lo16;
        if (col < KN) { if (cx) P[(size_t)m * KN + col] = f2bf(ap[n][j]); }
        else if (col == KN) out[OFF_BDY + m] = ap[1][j] + bb;
      }
    }
  }
  // per-wave complex ballot for phase A
  const int pbase = m0 + R;
  const int nvr = max(0, min(16, M_PTS - pbase));
  const unsigned mym = (lane < nvr) ? sVm[R + lane] : 0u;
  const unsigned long long cb = __ballot(__popc(mym) > 1);
  __syncthreads();   // all reads of sX/sQ/weights done -> overlays safe

  // load head weights into overlay region
  {
    const bf16x8* a = (const bf16x8*)(ws + WS_W1);
    const bf16x8* b = (const bf16x8*)(ws + WS_W2);
    for (int i = tid; i < 832; i += 256) ((bf16x8*)sW1)[i] = a[i];
    for (int i = tid; i < 208; i += 256) ((bf16x8*)sW2)[i] = b[i];
    if (tid < 16) sB2[tid] = ((const float*)(ws + WS_B2))[tid];
  }
  // affinity (simple rows): [1, 0, ..., 0]
  const int naff = nvr * KN;
#pragma unroll
  for (int it = 0; it < 7; ++it) {
    const int idx = it * 64 + lane;
    if (idx < naff) {
      const int p = idx / KN;
      if (!((cb >> p) & 1))
        out[OFF_AFF + (size_t)pbase * KN + idx] = (idx - p * KN == 0) ? 1.f : 0.f;
    }
  }
  // sS row = 2*sem[m] (simple rows)
  {
    const f4* semb = (const f4*)(sem + (size_t)pbase * CS);
    const int nf4 = nvr * 24;
#pragma unroll
    for (int it = 0; it < 6; ++it) {
      const int idx = it * 64 + lane;
      if (idx < nf4) {
        const f4 v = semb[idx];
        const int linear = idx * 4, p = linear / 96, c = linear - p * 96;
        if (!((cb >> p) & 1)) {
          s16x4 st;
          st[0] = f2bf(2.f * v.x); st[1] = f2bf(2.f * v.y);
          st[2] = f2bf(2.f * v.z); st[3] = f2bf(2.f * v.w);
          *(s16x4*)&sS[(R + p) * 104 + c] = st;
        }
      }
    }
  }
  __syncthreads();
  // head: rf = S@W1 + bout ; logits = S@W2 + b2  (complex rows get garbage; k2r overwrites)
  f32x4 ar[4] = {};
  f32x4 al = {};
#pragma unroll
  for (int kk = 0; kk < 3; ++kk) {
    const bf16x8 a = *(const bf16x8*)&sS[(R + lo16) * 104 + kk * 32 + hi4 * 8];
#pragma unroll
    for (int n = 0; n < 4; ++n) {
      const bf16x8 b = *(const bf16x8*)&sW1[(n * 16 + lo16) * 104 + kk * 32 + hi4 * 8];
      ar[n] = __builtin_amdgcn_mfma_f32_16x16x32_bf16(a, b, ar[n], 0, 0, 0);
    }
    const bf16x8 b = *(const bf16x8*)&sW2[lo16 * 104 + kk * 32 + hi4 * 8];
    al = __builtin_amdgcn_mfma_f32_16x16x32_bf16(a, b, al, 0, 0, 0);
  }
#pragma unroll
  for (int n = 0; n < 4; ++n) {
    const float bo = bout[n * 16 + lo16];
#pragma unroll
    for (int j = 0; j < 4; ++j) {
      const int m = m0 + R + hi4 * 4 + j;
      if (m < M_PTS) out[OFF_RF + (size_t)m * 64 + n * 16 + lo16] = ar[n][j] + bo;
    }
  }
  {
    const float bc = (lo16 < NC) ? sB2[lo16] : 0.f;
#pragma unroll
    for (int j = 0; j < 4; ++j) {
      const int m = m0 + R + hi4 * 4 + j;
      if (m < M_PTS && lo16 < NC) out[OFF_LOGITS + (size_t)m * NC + lo16] = al[j] + bc;
    }
  }
}

// ---------------- k2r: rare complex points (rescan vmask, full path, overwrite) ----------------
__global__ __launch_bounds__(256) void k2r(const float* __restrict__ sem,
                                           const int* __restrict__ coords,
                                           const void* __restrict__ nbrv,
                                           const float* __restrict__ bout,
                                           const short* __restrict__ ws,
                                           const short* __restrict__ Qg,
                                           const short* __restrict__ U,
                                           const short* __restrict__ P,
                                           const unsigned int* __restrict__ vmask,
                                           float* __restrict__ out) {
  __shared__ short sW1[6656];
  __shared__ short sW2[1664];
  __shared__ float sB2[16];
  const int tid = threadIdx.x;
  {
    const bf16x8* a = (const bf16x8*)(ws + WS_W1);
    const bf16x8* b = (const bf16x8*)(ws + WS_W2);
    for (int i = tid; i < 832; i += 256) ((bf16x8*)sW1)[i] = a[i];
    for (int i = tid; i < 208; i += 256) ((bf16x8*)sW2)[i] = b[i];
    if (tid < 16) sB2[tid] = ((const float*)(ws + WS_B2))[tid];
  }
  const bool is64 = nbr_is64(nbrv);
  __syncthreads();

  const int lane = tid & 63, w = tid >> 6;
  const int l31 = lane & 31;
  const float bo = bout[lane];
  const float bc = (lane < NC) ? sB2[lane] : 0.f;

  for (int tile = blockIdx.x * 4 + w; tile < NTILES; tile += gridDim.x * 4) {
    const int pbase = tile * 64;
    const int nv = min(64, M_PTS - pbase);
    const unsigned mym = (lane < nv) ? vmask[pbase + lane] : 0u;
    unsigned long long cbl = __ballot(__popc(mym) > 1);
    while (cbl) {
      const int p = __ffsll(cbl) - 1; cbl &= cbl - 1;
      const int m = pbase + p;
      int nk = 0, vf = 0, pidx = 13;
      if (lane < KN) {
        nk = (int)nbr_at(nbrv, is64, (size_t)m * KN + lane);
        const int dx = coords[nk * 3 + 0] - coords[m * 3 + 0];
        const int dy = coords[nk * 3 + 1] - coords[m * 3 + 1];
        const int dz = coords[nk * 3 + 2] - coords[m * 3 + 2];
        vf = (max(max(abs(dx), abs(dy)), abs(dz)) <= 1) ? 1 : 0;
        pidx = vf ? ((dx + 1) * 9 + (dy + 1) * 3 + (dz + 1)) : 13;
      }
      const float pval = (lane < KN) ? bf2f((unsigned short)P[(size_t)m * KN + pidx]) : 0.f;
      const float uv = bf2f((unsigned short)U[(size_t)m * 64 + lane]);
      float lg = -10000.f;
      unsigned long long vb = __ballot(vf != 0);
      while (vb) {
        const int k = __ffsll(vb) - 1; vb &= vb - 1;
        const int nn = __shfl(nk, k, 64);
        float dd = bf2f((unsigned short)Qg[(size_t)nn * 64 + lane]) * uv;
#pragma unroll
        for (int o = 1; o < 64; o <<= 1) dd += __shfl_xor(dd, o, 64);
        const float pv = __shfl(pval, k, 64);
        if (lane == k) lg = (dd + pv) * 0.125f;
      }
      float mx = lg;
#pragma unroll
      for (int o = 1; o < 32; o <<= 1) mx = fmaxf(mx, __shfl_xor(mx, o, 64));
      const float e = (lane < KN) ? __expf(lg - mx) : 0.f;
      float ssum = e;
#pragma unroll
      for (int o = 1; o < 32; o <<= 1) ssum += __shfl_xor(ssum, o, 64);
      const float aa = e / ssum;
      if (lane < KN) out[OFF_AFF + (size_t)m * KN + lane] = aa;
      float slo = sem[(size_t)m * CS + lane];
      float shi = sem[(size_t)m * CS + 64 + l31];
      unsigned long long ab = __ballot(lane < KN && aa > 0.f);
      while (ab) {
        const int k = __ffsll(ab) - 1; ab &= ab - 1;
        const float ak = __shfl(aa, k, 64);
        const int nn = __shfl(nk, k, 64);
        slo = fmaf(ak, sem[(size_t)nn * CS + lane], slo);
        shi = fmaf(ak, sem[(size_t)nn * CS + 64 + l31], shi);
      }
      // head matvec for this row: rf[d]/logits[j]
      float rf = bo, lgt = bc;
      for (int s = 0; s < 96; ++s) {
        const float as = (s < 64) ? __shfl(slo, s, 64) : __shfl(shi, s - 64, 64);
        rf = fmaf(as, bf2f((unsigned short)sW1[lane * 104 + s]), rf);
        if (lane < NC) lgt = fmaf(as, bf2f((unsigned short)sW2[lane * 104 + s]), lgt);
      }
      out[OFF_RF + (size_t)m * 64 + lane] = rf;
      if (lane < NC) out[OFF_LOGITS + (size_t)m * NC + lane] = lgt;
    }
  }
}

extern "C" void kernel_launch(void* const* d_in, const int* in_sizes, int n_in,
                              void* d_out, int out_size, void* d_ws, size_t ws_size,
                              hipStream_t stream) {
  const float* geo = (const float*)d_in[0];
  const float* sem = (const float*)d_in[1];
  const int* coords = (const int*)d_in[2];
  const void* nbrv = (const void*)d_in[3];
  const float* Wgeo = (const float*)d_in[4];
  const float* gamma = (const float*)d_in[5];
  const float* beta = (const float*)d_in[6];
  const float* Wbdy = (const float*)d_in[7];
  const float* bbdy = (const float*)d_in[8];
  const float* Wq = (const float*)d_in[9];
  const float* Wk = (const float*)d_in[10];
  const float* Wv = (const float*)d_in[11];
  const float* pos = (const float*)d_in[12];
  const float* Wout = (const float*)d_in[13];
  const float* bout = (const float*)d_in[14];
  const float* Wcls = (const float*)d_in[15];
  const float* bcls = (const float*)d_in[16];

  short* ws = (short*)d_ws;
  short* Qg = ws + WS_QG;
  short* U = ws + WS_U;
  short* P = ws + WS_P;
  unsigned int* vmask = (unsigned int*)(ws + WS_VM);
  float* out = (float*)d_out;

  k0<<<38, 256, 0, stream>>>(Wgeo, Wbdy, Wq, Wk, Wv, pos, Wout, bout, Wcls, bcls, ws);
  k1<<<NTILES, 256, 0, stream>>>(geo, sem, coords, nbrv, gamma, beta, bbdy, bout,
                                 ws, Qg, U, P, vmask, out);
  k2r<<<128, 256, 0, stream>>>(sem, coords, nbrv, bout, ws, Qg, U, P, vmask, out);
}